// Round 20
// baseline (206.198 us; speedup 1.0000x reference)
//
#include <hip/hip_runtime.h>

#define DEV __device__ __forceinline__

typedef __attribute__((ext_vector_type(8))) short short8;
typedef __bf16 bf16x8 __attribute__((ext_vector_type(8)));
typedef __attribute__((ext_vector_type(4))) float f32x4;

constexpr int NB = 16;
constexpr int NN = 64;
constexpr int ND = 512;
constexpr int NH = 8;

DEV float b2f(unsigned short h) { return __uint_as_float(((unsigned)h) << 16); }
DEV unsigned short f2b(float f) {
    unsigned u = __float_as_uint(f);
    return (unsigned short)((u + 0x7fffu + ((u >> 16) & 1u)) >> 16);
}
// mish(x) = x*(t^2+2t)/(t^2+2t+2), t=e^x; x>15 -> x
DEV float mish_fast(float x) {
    float t = __expf(x);
    float w = t * (t + 2.0f);
    float r = x * w * __builtin_amdgcn_rcpf(w + 2.0f);
    return (x > 15.0f) ? x : r;
}
DEV void gload16(const unsigned short* g, unsigned short* lds) {
    __builtin_amdgcn_global_load_lds((const __attribute__((address_space(1))) void*)g,
                                     (__attribute__((address_space(3))) void*)lds,
                                     16, 0, 0);
}

// ---------------------------------------------------------------------------
__global__ __launch_bounds__(64)
void probe_dtype(const unsigned* __restrict__ adj, int* __restrict__ flag)
{
    int t = threadIdx.x;
    int c = 0;
#pragma unroll
    for (int i = 0; i < 4; ++i) c += (int)((adj[t * 4 + i] >> 15) & 1u);
    for (int off = 32; off; off >>= 1) c += __shfl_xor(c, off);
    if (t == 0) flag[0] = (c > 32) ? 1 : 0;
}

// ---------------------------------------------------------------------------
// Weights -> FRAG-MAJOR bf16: Wt2[(k>>5)*16384 + c*32 + (k&31)] = W[k][c]
// (a wave's B-fragment = one contiguous 1 KB load)
// ---------------------------------------------------------------------------
__global__ __launch_bounds__(256)
void wtrans2(const void* W0, const void* W1, const void* W2, const void* W3,
             const void* W4, unsigned short* __restrict__ out,
             const int* __restrict__ flag)
{
    const void* W = (blockIdx.z == 0) ? W0 : (blockIdx.z == 1) ? W1 :
                    (blockIdx.z == 2) ? W2 : (blockIdx.z == 3) ? W3 : W4;
    const int f32 = flag[0];
    unsigned short* o = out + (size_t)blockIdx.z * 262144;
    __shared__ unsigned short tile[64][65];
    const int t = threadIdx.x;
    const int k0 = blockIdx.x * 64, c0 = blockIdx.y * 64;
#pragma unroll
    for (int rep = 0; rep < 16; ++rep) {
        int idx = rep * 256 + t;
        int r = idx >> 6, c = idx & 63;
        size_t gi = (size_t)(k0 + r) * 512 + c0 + c;
        float v = f32 ? ((const float*)W)[gi]
                      : b2f(((const unsigned short*)W)[gi]);
        tile[r][c] = f2b(v);
    }
    __syncthreads();
#pragma unroll
    for (int rep = 0; rep < 16; ++rep) {
        int idx = rep * 256 + t;
        int cc = idx >> 6, kk = idx & 63;
        int k = k0 + kk;
        o[(size_t)(k >> 5) * 16384 + (size_t)(c0 + cc) * 32 + (k & 31)] = tile[kk][cc];
    }
}

// ---------------------------------------------------------------------------
// GEMM v13 (r16/r19, measured best 195.5/196.1 us): A staged once to 64 KB
// LDS (slot g^(r&7)); B straight global->VGPR from frag-major Wt2 with
// explicit depth-1 ping-pong (bfA/bfB, static indices); ONE barrier;
// setprio around MFMA clusters. 512 thr / 8 waves, wave tile 64x64.
// AMODE: 0 = raw input (f32 per flag / bf16), 1 = bf16, 2 = bf16 * msg.
// In-place safe when A/out alias: ALL global A reads precede the staging
// barrier; writes after the K-loop; blocks own disjoint 64-row ranges.
// ---------------------------------------------------------------------------
template<int AMODE, bool MISH, bool OUTF32>
__global__ __launch_bounds__(512, 3)
void gemm13(const void* A, long long apitch,
            const unsigned short* __restrict__ Bt2,
            const void* __restrict__ bias_raw,
            const float* __restrict__ msg,
            void* out, long long opitch,
            const int* __restrict__ flag,
            const void* A2, const unsigned short* Bt2b,
            const void* bias2, void* out2)
{
    __shared__ alignas(16) unsigned short As[64][512];   // 64 KB
    const int f32g = flag[0];
    const int t = threadIdx.x;
    const int lane = t & 63;
    const int wv = t >> 6;           // 0..7 = 64-col panel

    long long row0;
    const void* Ap = A; const unsigned short* Btp = Bt2;
    const void* biasp = bias_raw; void* outp = out;
    if (A2 != nullptr && (int)blockIdx.x >= (int)(gridDim.x >> 1)) {
        Ap = A2; Btp = Bt2b; biasp = bias2; outp = out2;
        row0 = (long long)(blockIdx.x - (gridDim.x >> 1)) * 64;
    } else {
        row0 = (long long)blockIdx.x * 64;
    }

    // ---- stage the whole A panel once (64 rows x 512 k, swizzled bf16) ----
    {
        const int r = t >> 3;            // row 0..63
        const int q = t & 7;             // granule phase 0..7
        const long long gr = row0 + r;
        const float* mrow = nullptr;
        if (AMODE == 2) {
            int b = (int)(gr >> 12), m = (int)(gr >> 6) & 63, n = (int)gr & 63;
            mrow = msg + (((long long)b * 8) * 64 + m) * 64 + n;   // + head*4096
        }
        if (AMODE == 0 && f32g) {
            const float* Af = (const float*)Ap + gr * apitch;
#pragma unroll
            for (int i = 0; i < 8; ++i) {
                int g = q + 8 * i;       // granule 0..63; head = i
                f32x4 x0 = *reinterpret_cast<const f32x4*>(Af + g * 8);
                f32x4 x1 = *reinterpret_cast<const f32x4*>(Af + g * 8 + 4);
                short8 sv;
#pragma unroll
                for (int j = 0; j < 4; ++j) {
                    sv[j]     = (short)f2b(x0[j]);
                    sv[j + 4] = (short)f2b(x1[j]);
                }
                *reinterpret_cast<short8*>(&As[r][(g ^ (r & 7)) * 8]) = sv;
            }
        } else {
            const unsigned short* Ah = (const unsigned short*)Ap + gr * apitch;
#pragma unroll
            for (int i = 0; i < 8; ++i) {
                int g = q + 8 * i;
                short8 v = *reinterpret_cast<const short8*>(Ah + g * 8);
                if (AMODE == 2) {
                    float sc = mrow[i * 4096];          // head = i
#pragma unroll
                    for (int j = 0; j < 8; ++j)
                        v[j] = (short)f2b(b2f((unsigned short)v[j]) * sc);
                }
                *reinterpret_cast<short8*>(&As[r][(g ^ (r & 7)) * 8]) = v;
            }
        }
    }
    __syncthreads();      // the ONLY synchronization in this kernel

    const int rA = lane & 15;
    const int p  = lane >> 4;
    // frag-major B: wave wv, frag ni, step s -> 1 KB contiguous at
    //   Btp + s*16384 + (wv*64 + ni*16)*32 + rA*32 + p*8
    const unsigned short* bbase = Btp + ((size_t)(wv * 64 + rA) * 32 + p * 8);

    f32x4 acc[4][4];
#pragma unroll
    for (int mi = 0; mi < 4; ++mi)
#pragma unroll
        for (int ni = 0; ni < 4; ++ni) acc[mi][ni] = f32x4{0.f, 0.f, 0.f, 0.f};

    // ---- K-loop: 16 steps, barrier-free, explicit B ping-pong prefetch ----
    bf16x8 bfA[4], bfB[4];
#pragma unroll
    for (int ni = 0; ni < 4; ++ni)
        bfA[ni] = *reinterpret_cast<const bf16x8*>(bbase + (size_t)0 + ni * 512);

#pragma unroll
    for (int s2 = 0; s2 < 8; ++s2) {
        const int s = 2 * s2;
        // prefetch B(s+1) before consuming B(s)
#pragma unroll
        for (int ni = 0; ni < 4; ++ni)
            bfB[ni] = *reinterpret_cast<const bf16x8*>(
                bbase + (size_t)(s + 1) * 16384 + ni * 512);
        {
            bf16x8 af[4];
#pragma unroll
            for (int mi = 0; mi < 4; ++mi)
                af[mi] = *reinterpret_cast<const bf16x8*>(
                    &As[mi * 16 + rA][((s * 4 + p) ^ (rA & 7)) * 8]);
            __builtin_amdgcn_s_setprio(1);
#pragma unroll
            for (int mi = 0; mi < 4; ++mi)
#pragma unroll
                for (int ni = 0; ni < 4; ++ni)
                    acc[mi][ni] = __builtin_amdgcn_mfma_f32_16x16x32_bf16(
                        af[mi], bfA[ni], acc[mi][ni], 0, 0, 0);
            __builtin_amdgcn_s_setprio(0);
        }
        // prefetch B(s+2) before consuming B(s+1)
        if (s2 < 7) {
#pragma unroll
            for (int ni = 0; ni < 4; ++ni)
                bfA[ni] = *reinterpret_cast<const bf16x8*>(
                    bbase + (size_t)(s + 2) * 16384 + ni * 512);
        }
        {
            bf16x8 af[4];
#pragma unroll
            for (int mi = 0; mi < 4; ++mi)
                af[mi] = *reinterpret_cast<const bf16x8*>(
                    &As[mi * 16 + rA][(((s + 1) * 4 + p) ^ (rA & 7)) * 8]);
            __builtin_amdgcn_s_setprio(1);
#pragma unroll
            for (int mi = 0; mi < 4; ++mi)
#pragma unroll
                for (int ni = 0; ni < 4; ++ni)
                    acc[mi][ni] = __builtin_amdgcn_mfma_f32_16x16x32_bf16(
                        af[mi], bfB[ni], acc[mi][ni], 0, 0, 0);
            __builtin_amdgcn_s_setprio(0);
        }
    }

    // ---- epilogue: C/D layout col=lane&15, row=(lane>>4)*4+rr ----
    const int orow_q = (lane >> 4) * 4;
#pragma unroll
    for (int mi = 0; mi < 4; ++mi) {
#pragma unroll
        for (int ni = 0; ni < 4; ++ni) {
            int col = wv * 64 + ni * 16 + rA;
            float bz = f32g ? ((const float*)biasp)[col]
                            : b2f(((const unsigned short*)biasp)[col]);
            long long rbase = row0 + mi * 16 + orow_q;
#pragma unroll
            for (int rr = 0; rr < 4; ++rr) {
                float v = acc[mi][ni][rr] + bz;
                if (MISH) v = mish_fast(v);
                long long oi = (rbase + rr) * opitch + col;
                if (OUTF32) ((float*)outp)[oi] = v;
                else        ((unsigned short*)outp)[oi] = f2b(v);
            }
        }
    }
}

// ---------------------------------------------------------------------------
// Pass A: raw scores, kp read EXACTLY ONCE (verified rounds 6-19).
// kpp = kp row pitch in shorts (512 contiguous-in-ws, or 1024 aliased).
// ---------------------------------------------------------------------------
__global__ __launch_bounds__(256)
void score_kernel(const unsigned short* __restrict__ q,
                  const unsigned short* __restrict__ kp, long long kpp,
                  float* __restrict__ outS,
                  float* __restrict__ inS)
{
    const int bid = blockIdx.x;            // 512 blocks
    const int b  = bid >> 5;
    const int i0 = ((bid >> 2) & 7) * 8;
    const int j0 = (bid & 3) * 16;
    const int t = threadIdx.x, lane = t & 63, wv = t >> 6;

    __shared__ alignas(16) unsigned short qs[24][512];
    __shared__ float souts[8][16][8];
    __shared__ float sins[16][8][8];

#pragma unroll
    for (int r8 = 0; r8 < 6; ++r8) {
        int r = wv * 6 + r8;
        int grow = (r < 8) ? (i0 + r) : (j0 + r - 8);
        gload16(q + ((long long)(b * 64 + grow)) * 512 + lane * 8, &qs[r][0]);
    }
    __syncthreads();

    for (int batch = 0; batch < 4; ++batch) {
        const int rbase = wv * 32 + batch * 8;
        short8 kv[8];
#pragma unroll
        for (int u = 0; u < 8; ++u) {
            int r = rbase + u;
            int ii = r >> 4, jj = r & 15;
            kv[u] = *reinterpret_cast<const short8*>(
                kp + ((long long)((b * 64 + i0 + ii) * 64) + j0 + jj) * kpp + lane * 8);
        }
#pragma unroll
        for (int u = 0; u < 8; ++u) {
            int r = rbase + u;
            int ii = r >> 4, jj = r & 15;
            short8 qi = *reinterpret_cast<const short8*>(&qs[ii][lane * 8]);
            short8 qj = *reinterpret_cast<const short8*>(&qs[8 + jj][lane * 8]);
            float so = 0.f, si = 0.f;
#pragma unroll
            for (int e = 0; e < 8; ++e) {
                float kf = b2f((unsigned short)kv[u][e]);
                so += kf * b2f((unsigned short)qi[e]);
                si += kf * b2f((unsigned short)qj[e]);
            }
#pragma unroll
            for (int off = 1; off < 8; off <<= 1) {
                so += __shfl_xor(so, off);
                si += __shfl_xor(si, off);
            }
            if ((lane & 7) == 0) {
                souts[ii][jj][lane >> 3] = so * 0.125f;
                sins[jj][ii][lane >> 3]  = si * 0.125f;
            }
        }
    }
    __syncthreads();

    {
        int h  = t >> 5;
        int ii = (t >> 2) & 7;
        int qq = t & 3;
        f32x4 v;
#pragma unroll
        for (int e = 0; e < 4; ++e) v[e] = souts[ii][qq * 4 + e][h];
        *reinterpret_cast<f32x4*>(
            &outS[(((long long)(b * 8 + h) * 64) + i0 + ii) * 64 + j0 + qq * 4]) = v;
    }
    {
        int h  = t >> 5;
        int jj = (t >> 1) & 15;
        int hf = t & 1;
        f32x4 v;
#pragma unroll
        for (int e = 0; e < 4; ++e) v[e] = sins[jj][hf * 4 + e][h];
        *reinterpret_cast<f32x4*>(
            &inS[(((long long)(b * 8 + h) * 64) + j0 + jj) * 64 + i0 + hf * 4]) = v;
    }
}

// ---------------------------------------------------------------------------
__global__ __launch_bounds__(256)
void softmax_combine(float* __restrict__ outS, const float* __restrict__ inS)
{
    const long long row = (long long)blockIdx.x * 4 + (threadIdx.x >> 6);
    const int l = threadIdx.x & 63;
    const int x = (int)(row & 63);
    float so = outS[row * 64 + l];
    float si = inS[row * 64 + l];
    float mo = so, mi = si;
    for (int off = 32; off; off >>= 1) {
        mo = fmaxf(mo, __shfl_xor(mo, off));
        mi = fmaxf(mi, __shfl_xor(mi, off));
    }
    float eo = __expf(so - mo), ei = __expf(si - mi);
    float zo = eo, zi = ei;
    for (int off = 32; off; off >>= 1) {
        zo += __shfl_xor(zo, off);
        zi += __shfl_xor(zi, off);
    }
    float ao = eo / zo, ai = ei / zi;
    outS[row * 64 + l] = (l == x) ? ai : (ao + ai);
}

// ---------------------------------------------------------------------------
__global__ __launch_bounds__(512)
void nh_kernel(const float* __restrict__ msg,
               const unsigned short* __restrict__ v,
               unsigned short* __restrict__ nh)
{
    const int bm = blockIdx.x;
    const int b = bm >> 6, m = bm & 63;
    const int t = threadIdx.x;
    __shared__ float ms2[8 * 64];
    ms2[t] = msg[((long long)b * 8 + (t >> 6)) * 4096 + m * 64 + (t & 63)];
    __syncthreads();
    const float* mrow = &ms2[(t >> 6) * 64];
    float acc = 0.f;
#pragma unroll 8
    for (int n = 0; n < 64; ++n)
        acc += mrow[n] * b2f(v[((long long)b * 64 + n) * 512 + t]);
    nh[(long long)bm * 1024 + t] = f2b(acc);
}

// ---------------------------------------------------------------------------
extern "C" void kernel_launch(void* const* d_in, const int* in_sizes, int n_in,
                              void* d_out, int out_size, void* d_ws, size_t ws_size,
                              hipStream_t stream)
{
    const void* qn = d_in[0];
    const void* vn = d_in[1];
    const void* ke = d_in[2];
    const unsigned* adj = (const unsigned*)d_in[3];
    const void* Wq = d_in[4];  const void* bq = d_in[5];
    const void* Wk = d_in[6];  const void* bk = d_in[7];
    const void* Wv = d_in[8];  const void* bv = d_in[9];
    const void* Wn = d_in[10]; const void* bn = d_in[11];
    const void* We = d_in[12]; const void* be = d_in[13];

    float* out_node = (float*)d_out;                       // 16*64*512 f32 (2 MB)
    float* out_edge = out_node + (size_t)NB * NN * ND;     // 16*64*64*512 f32
    unsigned short* nh = (unsigned short*)out_node;        // bf16, pitch 1024 shorts
    float* inS = out_node;  // in-scores scratch (2 MB) — dead before nh_kernel

    char* wsb = (char*)d_ws;
    int* flag = (int*)wsb;
    unsigned short* Wt  = (unsigned short*)(wsb + 16);     // 5 x 512 KB (frag-major)
    unsigned short* Wqt = Wt + 0 * 262144;
    unsigned short* Wkt = Wt + 1 * 262144;
    unsigned short* Wvt = Wt + 2 * 262144;
    unsigned short* Wnt = Wt + 3 * 262144;
    unsigned short* Wet = Wt + 4 * 262144;
    unsigned short* q_ws = Wt + 5 * 262144;                // 1 MB bf16
    unsigned short* v_ws = q_ws + 524288;                  // 1 MB bf16
    float* msg = (float*)(v_ws + 524288);                  // 2 MB f32
    unsigned short* kp_ws = (unsigned short*)(msg + 524288); // 64 MB bf16 (optional)
    // base ws use ~6.5 MB; +64 MB if kp fits in ws

    // kp placement: contiguous in ws (pitch 512) if the workspace is big
    // enough, else strided-aliased into the edge f32 output region (pitch
    // 1024; bytes [r*2048, +1024) per row == the rows its f32 output later
    // overwrites — r19-proven in-place-safe path).
    const size_t kp_end = (size_t)((char*)(kp_ws + (size_t)33554432) - wsb);
    const bool kp_in_ws = ws_size >= kp_end;
    unsigned short* kp = kp_in_ws ? kp_ws : (unsigned short*)out_edge;
    const long long kpp = kp_in_ws ? 512 : 1024;

    probe_dtype<<<1, 64, 0, stream>>>(adj, flag);
    wtrans2<<<dim3(8, 8, 5), 256, 0, stream>>>(Wq, Wk, Wv, Wn, We, Wt, flag);
    // q + v projections merged (f32 A): blocks 0-15 -> q, 16-31 -> v
    gemm13<0, false, false><<<32, 512, 0, stream>>>(
        qn, 512, Wqt, bq, nullptr, q_ws, 512, flag, vn, Wvt, bv, v_ws);
    // k projection -> kp (ws-contiguous or strided-aliased)
    gemm13<0, false, false><<<1024, 512, 0, stream>>>(
        ke, 512, Wkt, bk, nullptr, kp, kpp, flag, nullptr, nullptr, nullptr, nullptr);
    // message: raw scores (kp read once) + softmax/combine
    score_kernel<<<512, 256, 0, stream>>>(q_ws, kp, kpp, msg, inS);
    softmax_combine<<<2048, 256, 0, stream>>>(msg, inS);
    // node path
    nh_kernel<<<NB * NN, 512, 0, stream>>>(msg, v_ws, nh);
    gemm13<1, true, true><<<16, 512, 0, stream>>>(
        nh, 1024, Wnt, bn, nullptr, out_node, 512, flag, nullptr, nullptr, nullptr, nullptr);
    // edge path: msg-scaling fused into A-staging (in-place-safe if aliased)
    gemm13<2, true, true><<<1024, 512, 0, stream>>>(
        kp, kpp, Wet, be, msg, out_edge, 512, flag, nullptr, nullptr, nullptr, nullptr);
}

// Round 21
// 195.530 us; speedup vs baseline: 1.0546x; 1.0546x over previous
//
#include <hip/hip_runtime.h>

#define DEV __device__ __forceinline__

typedef __attribute__((ext_vector_type(8))) short short8;
typedef __bf16 bf16x8 __attribute__((ext_vector_type(8)));
typedef __attribute__((ext_vector_type(4))) float f32x4;

constexpr int NB = 16;
constexpr int NN = 64;
constexpr int ND = 512;
constexpr int NH = 8;

DEV float b2f(unsigned short h) { return __uint_as_float(((unsigned)h) << 16); }
DEV unsigned short f2b(float f) {
    unsigned u = __float_as_uint(f);
    return (unsigned short)((u + 0x7fffu + ((u >> 16) & 1u)) >> 16);
}
// mish(x) = x*(t^2+2t)/(t^2+2t+2), t=e^x; x>15 -> x
DEV float mish_fast(float x) {
    float t = __expf(x);
    float w = t * (t + 2.0f);
    float r = x * w * __builtin_amdgcn_rcpf(w + 2.0f);
    return (x > 15.0f) ? x : r;
}
DEV void gload16(const unsigned short* g, unsigned short* lds) {
    __builtin_amdgcn_global_load_lds((const __attribute__((address_space(1))) void*)g,
                                     (__attribute__((address_space(3))) void*)lds,
                                     16, 0, 0);
}

// ---------------------------------------------------------------------------
__global__ __launch_bounds__(64)
void probe_dtype(const unsigned* __restrict__ adj, int* __restrict__ flag)
{
    int t = threadIdx.x;
    int c = 0;
#pragma unroll
    for (int i = 0; i < 4; ++i) c += (int)((adj[t * 4 + i] >> 15) & 1u);
    for (int off = 32; off; off >>= 1) c += __shfl_xor(c, off);
    if (t == 0) flag[0] = (c > 32) ? 1 : 0;
}

// ---------------------------------------------------------------------------
// Weights -> FRAG-MAJOR bf16: Wt2[(k>>5)*16384 + c*32 + (k&31)] = W[k][c]
// (a wave's B-fragment = one contiguous 1 KB load)
// ---------------------------------------------------------------------------
__global__ __launch_bounds__(256)
void wtrans2(const void* W0, const void* W1, const void* W2, const void* W3,
             const void* W4, unsigned short* __restrict__ out,
             const int* __restrict__ flag)
{
    const void* W = (blockIdx.z == 0) ? W0 : (blockIdx.z == 1) ? W1 :
                    (blockIdx.z == 2) ? W2 : (blockIdx.z == 3) ? W3 : W4;
    const int f32 = flag[0];
    unsigned short* o = out + (size_t)blockIdx.z * 262144;
    __shared__ unsigned short tile[64][65];
    const int t = threadIdx.x;
    const int k0 = blockIdx.x * 64, c0 = blockIdx.y * 64;
#pragma unroll
    for (int rep = 0; rep < 16; ++rep) {
        int idx = rep * 256 + t;
        int r = idx >> 6, c = idx & 63;
        size_t gi = (size_t)(k0 + r) * 512 + c0 + c;
        float v = f32 ? ((const float*)W)[gi]
                      : b2f(((const unsigned short*)W)[gi]);
        tile[r][c] = f2b(v);
    }
    __syncthreads();
#pragma unroll
    for (int rep = 0; rep < 16; ++rep) {
        int idx = rep * 256 + t;
        int cc = idx >> 6, kk = idx & 63;
        int k = k0 + kk;
        o[(size_t)(k >> 5) * 16384 + (size_t)(c0 + cc) * 32 + (k & 31)] = tile[kk][cc];
    }
}

// ---------------------------------------------------------------------------
// GEMM v13 (r16/r19, measured best 195.5/196.1 us): A staged once to 64 KB
// LDS (slot g^(r&7)); B straight global->VGPR from frag-major Wt2 with
// explicit depth-1 ping-pong (bfA/bfB, static indices); ONE barrier;
// setprio around MFMA clusters. 512 thr / 8 waves, wave tile 64x64.
// AMODE: 0 = raw input (f32 per flag / bf16), 1 = bf16, 2 = bf16 * msg.
// In-place safe: ALL global A reads precede the staging barrier; writes
// after the K-loop; blocks own disjoint 64-row ranges.
// ---------------------------------------------------------------------------
template<int AMODE, bool MISH, bool OUTF32>
__global__ __launch_bounds__(512, 3)
void gemm13(const void* A, long long apitch,
            const unsigned short* __restrict__ Bt2,
            const void* __restrict__ bias_raw,
            const float* __restrict__ msg,
            void* out, long long opitch,
            const int* __restrict__ flag,
            const void* A2, const unsigned short* Bt2b,
            const void* bias2, void* out2)
{
    __shared__ alignas(16) unsigned short As[64][512];   // 64 KB
    const int f32g = flag[0];
    const int t = threadIdx.x;
    const int lane = t & 63;
    const int wv = t >> 6;           // 0..7 = 64-col panel

    long long row0;
    const void* Ap = A; const unsigned short* Btp = Bt2;
    const void* biasp = bias_raw; void* outp = out;
    if (A2 != nullptr && (int)blockIdx.x >= (int)(gridDim.x >> 1)) {
        Ap = A2; Btp = Bt2b; biasp = bias2; outp = out2;
        row0 = (long long)(blockIdx.x - (gridDim.x >> 1)) * 64;
    } else {
        row0 = (long long)blockIdx.x * 64;
    }

    // ---- stage the whole A panel once (64 rows x 512 k, swizzled bf16) ----
    {
        const int r = t >> 3;            // row 0..63
        const int q = t & 7;             // granule phase 0..7
        const long long gr = row0 + r;
        const float* mrow = nullptr;
        if (AMODE == 2) {
            int b = (int)(gr >> 12), m = (int)(gr >> 6) & 63, n = (int)gr & 63;
            mrow = msg + (((long long)b * 8) * 64 + m) * 64 + n;   // + head*4096
        }
        if (AMODE == 0 && f32g) {
            const float* Af = (const float*)Ap + gr * apitch;
#pragma unroll
            for (int i = 0; i < 8; ++i) {
                int g = q + 8 * i;       // granule 0..63; head = i
                f32x4 x0 = *reinterpret_cast<const f32x4*>(Af + g * 8);
                f32x4 x1 = *reinterpret_cast<const f32x4*>(Af + g * 8 + 4);
                short8 sv;
#pragma unroll
                for (int j = 0; j < 4; ++j) {
                    sv[j]     = (short)f2b(x0[j]);
                    sv[j + 4] = (short)f2b(x1[j]);
                }
                *reinterpret_cast<short8*>(&As[r][(g ^ (r & 7)) * 8]) = sv;
            }
        } else {
            const unsigned short* Ah = (const unsigned short*)Ap + gr * apitch;
#pragma unroll
            for (int i = 0; i < 8; ++i) {
                int g = q + 8 * i;
                short8 v = *reinterpret_cast<const short8*>(Ah + g * 8);
                if (AMODE == 2) {
                    float sc = mrow[i * 4096];          // head = i
#pragma unroll
                    for (int j = 0; j < 8; ++j)
                        v[j] = (short)f2b(b2f((unsigned short)v[j]) * sc);
                }
                *reinterpret_cast<short8*>(&As[r][(g ^ (r & 7)) * 8]) = v;
            }
        }
    }
    __syncthreads();      // the ONLY synchronization in this kernel

    const int rA = lane & 15;
    const int p  = lane >> 4;
    // frag-major B: wave wv, frag ni, step s -> 1 KB contiguous at
    //   Btp + s*16384 + (wv*64 + ni*16)*32 + rA*32 + p*8
    const unsigned short* bbase = Btp + ((size_t)(wv * 64 + rA) * 32 + p * 8);

    f32x4 acc[4][4];
#pragma unroll
    for (int mi = 0; mi < 4; ++mi)
#pragma unroll
        for (int ni = 0; ni < 4; ++ni) acc[mi][ni] = f32x4{0.f, 0.f, 0.f, 0.f};

    // ---- K-loop: 16 steps, barrier-free, explicit B ping-pong prefetch ----
    bf16x8 bfA[4], bfB[4];
#pragma unroll
    for (int ni = 0; ni < 4; ++ni)
        bfA[ni] = *reinterpret_cast<const bf16x8*>(bbase + (size_t)0 + ni * 512);

#pragma unroll
    for (int s2 = 0; s2 < 8; ++s2) {
        const int s = 2 * s2;
        // prefetch B(s+1) before consuming B(s)
#pragma unroll
        for (int ni = 0; ni < 4; ++ni)
            bfB[ni] = *reinterpret_cast<const bf16x8*>(
                bbase + (size_t)(s + 1) * 16384 + ni * 512);
        {
            bf16x8 af[4];
#pragma unroll
            for (int mi = 0; mi < 4; ++mi)
                af[mi] = *reinterpret_cast<const bf16x8*>(
                    &As[mi * 16 + rA][((s * 4 + p) ^ (rA & 7)) * 8]);
            __builtin_amdgcn_s_setprio(1);
#pragma unroll
            for (int mi = 0; mi < 4; ++mi)
#pragma unroll
                for (int ni = 0; ni < 4; ++ni)
                    acc[mi][ni] = __builtin_amdgcn_mfma_f32_16x16x32_bf16(
                        af[mi], bfA[ni], acc[mi][ni], 0, 0, 0);
            __builtin_amdgcn_s_setprio(0);
        }
        // prefetch B(s+2) before consuming B(s+1)
        if (s2 < 7) {
#pragma unroll
            for (int ni = 0; ni < 4; ++ni)
                bfA[ni] = *reinterpret_cast<const bf16x8*>(
                    bbase + (size_t)(s + 2) * 16384 + ni * 512);
        }
        {
            bf16x8 af[4];
#pragma unroll
            for (int mi = 0; mi < 4; ++mi)
                af[mi] = *reinterpret_cast<const bf16x8*>(
                    &As[mi * 16 + rA][(((s + 1) * 4 + p) ^ (rA & 7)) * 8]);
            __builtin_amdgcn_s_setprio(1);
#pragma unroll
            for (int mi = 0; mi < 4; ++mi)
#pragma unroll
                for (int ni = 0; ni < 4; ++ni)
                    acc[mi][ni] = __builtin_amdgcn_mfma_f32_16x16x32_bf16(
                        af[mi], bfB[ni], acc[mi][ni], 0, 0, 0);
            __builtin_amdgcn_s_setprio(0);
        }
    }

    // ---- epilogue: C/D layout col=lane&15, row=(lane>>4)*4+rr ----
    const int orow_q = (lane >> 4) * 4;
#pragma unroll
    for (int mi = 0; mi < 4; ++mi) {
#pragma unroll
        for (int ni = 0; ni < 4; ++ni) {
            int col = wv * 64 + ni * 16 + rA;
            float bz = f32g ? ((const float*)biasp)[col]
                            : b2f(((const unsigned short*)biasp)[col]);
            long long rbase = row0 + mi * 16 + orow_q;
#pragma unroll
            for (int rr = 0; rr < 4; ++rr) {
                float v = acc[mi][ni][rr] + bz;
                if (MISH) v = mish_fast(v);
                long long oi = (rbase + rr) * opitch + col;
                if (OUTF32) ((float*)outp)[oi] = v;
                else        ((unsigned short*)outp)[oi] = f2b(v);
            }
        }
    }
}

// ---------------------------------------------------------------------------
// Pass A: raw scores, kp read EXACTLY ONCE (verified rounds 6-20).
// ---------------------------------------------------------------------------
__global__ __launch_bounds__(256)
void score_kernel(const unsigned short* __restrict__ q,
                  const unsigned short* __restrict__ kp,
                  float* __restrict__ outS,
                  float* __restrict__ inS)
{
    const int bid = blockIdx.x;            // 512 blocks
    const int b  = bid >> 5;
    const int i0 = ((bid >> 2) & 7) * 8;
    const int j0 = (bid & 3) * 16;
    const int t = threadIdx.x, lane = t & 63, wv = t >> 6;

    __shared__ alignas(16) unsigned short qs[24][512];
    __shared__ float souts[8][16][8];
    __shared__ float sins[16][8][8];

#pragma unroll
    for (int r8 = 0; r8 < 6; ++r8) {
        int r = wv * 6 + r8;
        int grow = (r < 8) ? (i0 + r) : (j0 + r - 8);
        gload16(q + ((long long)(b * 64 + grow)) * 512 + lane * 8, &qs[r][0]);
    }
    __syncthreads();

    for (int batch = 0; batch < 4; ++batch) {
        const int rbase = wv * 32 + batch * 8;
        short8 kv[8];
#pragma unroll
        for (int u = 0; u < 8; ++u) {
            int r = rbase + u;
            int ii = r >> 4, jj = r & 15;
            kv[u] = *reinterpret_cast<const short8*>(
                kp + ((long long)((b * 64 + i0 + ii) * 64) + j0 + jj) * 1024 + lane * 8);
        }
#pragma unroll
        for (int u = 0; u < 8; ++u) {
            int r = rbase + u;
            int ii = r >> 4, jj = r & 15;
            short8 qi = *reinterpret_cast<const short8*>(&qs[ii][lane * 8]);
            short8 qj = *reinterpret_cast<const short8*>(&qs[8 + jj][lane * 8]);
            float so = 0.f, si = 0.f;
#pragma unroll
            for (int e = 0; e < 8; ++e) {
                float kf = b2f((unsigned short)kv[u][e]);
                so += kf * b2f((unsigned short)qi[e]);
                si += kf * b2f((unsigned short)qj[e]);
            }
#pragma unroll
            for (int off = 1; off < 8; off <<= 1) {
                so += __shfl_xor(so, off);
                si += __shfl_xor(si, off);
            }
            if ((lane & 7) == 0) {
                souts[ii][jj][lane >> 3] = so * 0.125f;
                sins[jj][ii][lane >> 3]  = si * 0.125f;
            }
        }
    }
    __syncthreads();

    {
        int h  = t >> 5;
        int ii = (t >> 2) & 7;
        int qq = t & 3;
        f32x4 v;
#pragma unroll
        for (int e = 0; e < 4; ++e) v[e] = souts[ii][qq * 4 + e][h];
        *reinterpret_cast<f32x4*>(
            &outS[(((long long)(b * 8 + h) * 64) + i0 + ii) * 64 + j0 + qq * 4]) = v;
    }
    {
        int h  = t >> 5;
        int jj = (t >> 1) & 15;
        int hf = t & 1;
        f32x4 v;
#pragma unroll
        for (int e = 0; e < 4; ++e) v[e] = sins[jj][hf * 4 + e][h];
        *reinterpret_cast<f32x4*>(
            &inS[(((long long)(b * 8 + h) * 64) + j0 + jj) * 64 + i0 + hf * 4]) = v;
    }
}

// ---------------------------------------------------------------------------
__global__ __launch_bounds__(256)
void softmax_combine(float* __restrict__ outS, const float* __restrict__ inS)
{
    const long long row = (long long)blockIdx.x * 4 + (threadIdx.x >> 6);
    const int l = threadIdx.x & 63;
    const int x = (int)(row & 63);
    float so = outS[row * 64 + l];
    float si = inS[row * 64 + l];
    float mo = so, mi = si;
    for (int off = 32; off; off >>= 1) {
        mo = fmaxf(mo, __shfl_xor(mo, off));
        mi = fmaxf(mi, __shfl_xor(mi, off));
    }
    float eo = __expf(so - mo), ei = __expf(si - mi);
    float zo = eo, zi = ei;
    for (int off = 32; off; off >>= 1) {
        zo += __shfl_xor(zo, off);
        zi += __shfl_xor(zi, off);
    }
    float ao = eo / zo, ai = ei / zi;
    outS[row * 64 + l] = (l == x) ? ai : (ao + ai);
}

// ---------------------------------------------------------------------------
__global__ __launch_bounds__(512)
void nh_kernel(const float* __restrict__ msg,
               const unsigned short* __restrict__ v,
               unsigned short* __restrict__ nh)
{
    const int bm = blockIdx.x;
    const int b = bm >> 6, m = bm & 63;
    const int t = threadIdx.x;
    __shared__ float ms2[8 * 64];
    ms2[t] = msg[((long long)b * 8 + (t >> 6)) * 4096 + m * 64 + (t & 63)];
    __syncthreads();
    const float* mrow = &ms2[(t >> 6) * 64];
    float acc = 0.f;
#pragma unroll 8
    for (int n = 0; n < 64; ++n)
        acc += mrow[n] * b2f(v[((long long)b * 64 + n) * 512 + t]);
    nh[(long long)bm * 1024 + t] = f2b(acc);
}

// ---------------------------------------------------------------------------
extern "C" void kernel_launch(void* const* d_in, const int* in_sizes, int n_in,
                              void* d_out, int out_size, void* d_ws, size_t ws_size,
                              hipStream_t stream)
{
    const void* qn = d_in[0];
    const void* vn = d_in[1];
    const void* ke = d_in[2];
    const unsigned* adj = (const unsigned*)d_in[3];
    const void* Wq = d_in[4];  const void* bq = d_in[5];
    const void* Wk = d_in[6];  const void* bk = d_in[7];
    const void* Wv = d_in[8];  const void* bv = d_in[9];
    const void* Wn = d_in[10]; const void* bn = d_in[11];
    const void* We = d_in[12]; const void* be = d_in[13];

    float* out_node = (float*)d_out;                       // 16*64*512 f32 (2 MB)
    float* out_edge = out_node + (size_t)NB * NN * ND;     // 16*64*64*512 f32
    unsigned short* kp = (unsigned short*)out_edge;        // bf16, pitch 1024 shorts
    unsigned short* nh = (unsigned short*)out_node;        // bf16, pitch 1024 shorts
    float* inS = out_node;  // in-scores scratch (2 MB) — dead before nh_kernel

    char* wsb = (char*)d_ws;
    int* flag = (int*)wsb;
    unsigned short* Wt  = (unsigned short*)(wsb + 16);     // 5 x 512 KB (frag-major)
    unsigned short* Wqt = Wt + 0 * 262144;
    unsigned short* Wkt = Wt + 1 * 262144;
    unsigned short* Wvt = Wt + 2 * 262144;
    unsigned short* Wnt = Wt + 3 * 262144;
    unsigned short* Wet = Wt + 4 * 262144;
    unsigned short* q_ws = Wt + 5 * 262144;                // 1 MB bf16
    unsigned short* v_ws = q_ws + 524288;                  // 1 MB bf16
    float* msg = (float*)(v_ws + 524288);                  // 2 MB f32
    // ws total ~6.5 MB

    probe_dtype<<<1, 64, 0, stream>>>(adj, flag);
    wtrans2<<<dim3(8, 8, 5), 256, 0, stream>>>(Wq, Wk, Wv, Wn, We, Wt, flag);
    // q + v projections merged (f32 A): blocks 0-15 -> q, 16-31 -> v
    gemm13<0, false, false><<<32, 512, 0, stream>>>(
        qn, 512, Wqt, bq, nullptr, q_ws, 512, flag, vn, Wvt, bv, v_ws);
    // k projection -> strided bf16 inside the edge f32 output region
    gemm13<0, false, false><<<1024, 512, 0, stream>>>(
        ke, 512, Wkt, bk, nullptr, kp, 1024, flag, nullptr, nullptr, nullptr, nullptr);
    // message: raw scores (kp read once) + softmax/combine
    score_kernel<<<512, 256, 0, stream>>>(q_ws, kp, msg, inS);
    softmax_combine<<<2048, 256, 0, stream>>>(msg, inS);
    // node path
    nh_kernel<<<NB * NN, 512, 0, stream>>>(msg, v_ws, nh);
    gemm13<1, true, true><<<16, 512, 0, stream>>>(
        nh, 1024, Wnt, bn, nullptr, out_node, 512, flag, nullptr, nullptr, nullptr, nullptr);
    // edge path: msg-scaling fused into A-staging; in-place
    gemm13<2, true, true><<<1024, 512, 0, stream>>>(
        kp, 1024, Wet, be, msg, out_edge, 512, flag, nullptr, nullptr, nullptr, nullptr);
}